// Round 1
// baseline (4992.014 us; speedup 1.0000x reference)
//
#include <hip/hip_runtime.h>
#include <hip/hip_bf16.h>
#include <math.h>

// Perceiver: B=4,C=3,N=4096,E=256,H=8,L=512,FF*E=1024,D=4,NCLS=1000,HS=2048
// Per-head dim = E = 256; scale = 1/sqrt(E/H) = 1/sqrt(32).

// ---------------- tokens = conv1x1(x) + bias + pos ----------------
__global__ __launch_bounds__(256) void k_tokens(
    const float* __restrict__ x, const float* __restrict__ cw,
    const float* __restrict__ cb, const float* __restrict__ pe,
    float* __restrict__ tok)
{
  int idx = blockIdx.x * 256 + threadIdx.x;   // B*N*E = 4,194,304
  int e = idx & 255;
  int n = (idx >> 8) & 4095;
  int b = idx >> 20;
  float s = cb[e] + pe[n * 256 + e];
#pragma unroll
  for (int c = 0; c < 3; ++c)
    s += x[b * 12288 + c * 4096 + n] * cw[e * 3 + c];
  tok[idx] = s;
}

// ---------------- generic fp32 tiled GEMM: C = A(MxK) * B(KxN or NxK^T) ----
// 64x64 tile, BK=16, 256 threads, 4x4 micro-tile. batched via grid.z strides.
template<bool TRANSB>
__global__ __launch_bounds__(256) void k_gemm(
    const float* __restrict__ A, const float* __restrict__ B,
    float* __restrict__ C,
    int M, int N, int K, int lda, int ldb, int ldc,
    long sA, long sB, long sC)
{
  __shared__ float As[16][68];
  __shared__ float Bs[16][68];
  const float* Ab = A + (long)blockIdx.z * sA;
  const float* Bb = B + (long)blockIdx.z * sB;
  float* Cb = C + (long)blockIdx.z * sC;
  int tid = threadIdx.x;
  int tx = tid & 15, ty = tid >> 4;
  int row0 = blockIdx.y * 64, col0 = blockIdx.x * 64;
  int ar = tid >> 2, ac = (tid & 3) << 2;   // A loader: row ar (0..63), 4 cols
  int kr = tid >> 4, bc = (tid & 15) << 2;  // B loader (NN): k-row, 4 cols
  float acc[4][4] = {};
  for (int k0 = 0; k0 < K; k0 += 16) {
    float4 av = *reinterpret_cast<const float4*>(&Ab[(long)(row0 + ar) * lda + k0 + ac]);
    float4 bv;
    if (TRANSB)
      bv = *reinterpret_cast<const float4*>(&Bb[(long)(col0 + ar) * ldb + k0 + ac]);
    else
      bv = *reinterpret_cast<const float4*>(&Bb[(long)(k0 + kr) * ldb + col0 + bc]);
    __syncthreads();
    As[ac + 0][ar] = av.x; As[ac + 1][ar] = av.y;
    As[ac + 2][ar] = av.z; As[ac + 3][ar] = av.w;
    if (TRANSB) {
      Bs[ac + 0][ar] = bv.x; Bs[ac + 1][ar] = bv.y;
      Bs[ac + 2][ar] = bv.z; Bs[ac + 3][ar] = bv.w;
    } else {
      *reinterpret_cast<float4*>(&Bs[kr][bc]) = bv;
    }
    __syncthreads();
#pragma unroll
    for (int kk = 0; kk < 16; ++kk) {
      float4 a = *reinterpret_cast<const float4*>(&As[kk][ty << 2]);
      float4 b = *reinterpret_cast<const float4*>(&Bs[kk][tx << 2]);
      acc[0][0] += a.x*b.x; acc[0][1] += a.x*b.y; acc[0][2] += a.x*b.z; acc[0][3] += a.x*b.w;
      acc[1][0] += a.y*b.x; acc[1][1] += a.y*b.y; acc[1][2] += a.y*b.z; acc[1][3] += a.y*b.w;
      acc[2][0] += a.z*b.x; acc[2][1] += a.z*b.y; acc[2][2] += a.z*b.z; acc[2][3] += a.z*b.w;
      acc[3][0] += a.w*b.x; acc[3][1] += a.w*b.y; acc[3][2] += a.w*b.z; acc[3][3] += a.w*b.w;
    }
  }
#pragma unroll
  for (int i = 0; i < 4; ++i) {
    float4 c4 = make_float4(acc[i][0], acc[i][1], acc[i][2], acc[i][3]);
    *reinterpret_cast<float4*>(&Cb[(long)(row0 + (ty << 2) + i) * ldc + col0 + (tx << 2)]) = c4;
  }
}

// ---------------- unified flash attention (d=256 per head) ----------------
// 32 q-rows per block, 256 threads. Online softmax over nk in tiles of 32.
// Handles CA (K=V=tokens) and block self-attn via pointer/stride args.
__global__ __launch_bounds__(256) void k_flash(
    const float* __restrict__ Qp, const float* __restrict__ Kp,
    const float* __restrict__ Vp, float* __restrict__ Op,
    int nk, int sq, int sk, int sv, int so,
    long qHead, long qBatch, long kHead, long kBatch,
    long vHead, long vBatch, long oHead, long oBatch, float scale)
{
  __shared__ float Qs[32][260];
  __shared__ float Ks[32][260];
  __shared__ float Vs[32][260];
  __shared__ float Ps[32][33];
  int h = blockIdx.y, b = blockIdx.z;
  int q0 = blockIdx.x * 32;
  const float* Qb = Qp + h * qHead + b * qBatch;
  const float* Kb = Kp + h * kHead + b * kBatch;
  const float* Vb = Vp + h * vHead + b * vBatch;
  float* Ob = Op + h * oHead + b * oBatch;
  bool sameKV = (Kb == Vb);
  int tid = threadIdx.x;
  int qi = tid >> 3, j0 = tid & 7;
  int lr = tid >> 3, lc = (tid & 7) * 32;
#pragma unroll
  for (int ii = 0; ii < 8; ++ii)
    *reinterpret_cast<float4*>(&Qs[lr][lc + 4 * ii]) =
        *reinterpret_cast<const float4*>(&Qb[(long)(q0 + lr) * sq + lc + 4 * ii]);
  float O[8][4] = {};
  float mrow = -INFINITY, lrow = 0.f;
  for (int k0 = 0; k0 < nk; k0 += 32) {
#pragma unroll
    for (int ii = 0; ii < 8; ++ii)
      *reinterpret_cast<float4*>(&Ks[lr][lc + 4 * ii]) =
          *reinterpret_cast<const float4*>(&Kb[(long)(k0 + lr) * sk + lc + 4 * ii]);
    if (!sameKV) {
#pragma unroll
      for (int ii = 0; ii < 8; ++ii)
        *reinterpret_cast<float4*>(&Vs[lr][lc + 4 * ii]) =
            *reinterpret_cast<const float4*>(&Vb[(long)(k0 + lr) * sv + lc + 4 * ii]);
    }
    __syncthreads();
    // scores: thread computes s[qi][j0+8m], m=0..3
    float accv[4] = {0.f, 0.f, 0.f, 0.f};
    for (int c = 0; c < 256; c += 4) {
      float4 q = *reinterpret_cast<const float4*>(&Qs[qi][c]);
#pragma unroll
      for (int m = 0; m < 4; ++m) {
        float4 k = *reinterpret_cast<const float4*>(&Ks[j0 + 8 * m][c]);
        accv[m] += q.x * k.x + q.y * k.y + q.z * k.z + q.w * k.w;
      }
    }
#pragma unroll
    for (int m = 0; m < 4; ++m) accv[m] *= scale;
    float tmax = fmaxf(fmaxf(accv[0], accv[1]), fmaxf(accv[2], accv[3]));
#pragma unroll
    for (int o = 1; o < 8; o <<= 1) tmax = fmaxf(tmax, __shfl_xor(tmax, o));
    float mnew = fmaxf(mrow, tmax);
    float alpha = __expf(mrow - mnew);
    float psum = 0.f;
#pragma unroll
    for (int m = 0; m < 4; ++m) {
      float p = __expf(accv[m] - mnew);
      Ps[qi][j0 + 8 * m] = p;
      psum += p;
    }
#pragma unroll
    for (int o = 1; o < 8; o <<= 1) psum += __shfl_xor(psum, o);
    lrow = lrow * alpha + psum;
    mrow = mnew;
#pragma unroll
    for (int i = 0; i < 8; ++i) {
      O[i][0] *= alpha; O[i][1] *= alpha; O[i][2] *= alpha; O[i][3] *= alpha;
    }
    __syncthreads();
    const float (*Vu)[260] = sameKV ? (const float (*)[260])Ks : (const float (*)[260])Vs;
    for (int kj = 0; kj < 32; ++kj) {
      float p = Ps[qi][kj];
#pragma unroll
      for (int i = 0; i < 8; ++i) {
        float4 v = *reinterpret_cast<const float4*>(&Vu[kj][4 * j0 + 32 * i]);
        O[i][0] += p * v.x; O[i][1] += p * v.y; O[i][2] += p * v.z; O[i][3] += p * v.w;
      }
    }
    __syncthreads();
  }
  float inv = 1.f / lrow;
#pragma unroll
  for (int i = 0; i < 8; ++i) {
    float4 v = make_float4(O[i][0] * inv, O[i][1] * inv, O[i][2] * inv, O[i][3] * inv);
    *reinterpret_cast<float4*>(&Ob[(long)(q0 + qi) * so + 4 * j0 + 32 * i]) = v;
  }
}

// ---------------- out = LN(Y + bias + res) ----------------
__global__ __launch_bounds__(256) void k_bias_res_ln(
    const float* __restrict__ Y, const float* __restrict__ bias,
    const float* __restrict__ res, int resMod,
    const float* __restrict__ g, const float* __restrict__ bta,
    float* __restrict__ out)
{
  __shared__ float red[4];
  int row = blockIdx.x, e = threadIdx.x;
  float v = Y[(long)row * 256 + e] + bias[e] + res[(long)(row % resMod) * 256 + e];
  float s = v;
#pragma unroll
  for (int o = 32; o > 0; o >>= 1) s += __shfl_down(s, o);
  if ((e & 63) == 0) red[e >> 6] = s;
  __syncthreads();
  float mean = (red[0] + red[1] + red[2] + red[3]) * (1.f / 256.f);
  float d = v - mean;
  __syncthreads();
  float s2 = d * d;
#pragma unroll
  for (int o = 32; o > 0; o >>= 1) s2 += __shfl_down(s2, o);
  if ((e & 63) == 0) red[e >> 6] = s2;
  __syncthreads();
  float var = (red[0] + red[1] + red[2] + red[3]) * (1.f / 256.f);
  out[(long)row * 256 + e] = g[e] * d * rsqrtf(var + 1e-5f) + bta[e];
}

// ---------------- y = gelu(y + bias) (exact erf) ----------------
__global__ __launch_bounds__(256) void k_bias_gelu(
    float* __restrict__ y, const float* __restrict__ bias, int ncols)
{
  int i = blockIdx.x * 256 + threadIdx.x;
  float v = y[i] + bias[i % ncols];
  y[i] = 0.5f * v * (1.f + erff(v * 0.70710678118654752f));
}

// ---------------- zm[b,e] = mean_l z[b,l,e] ----------------
__global__ __launch_bounds__(256) void k_mean(const float* __restrict__ z,
                                              float* __restrict__ zm)
{
  int b = blockIdx.x, e = threadIdx.x;
  float s = 0.f;
  for (int l = 0; l < 512; ++l) s += z[((long)b * 512 + l) * 256 + e];
  zm[b * 256 + e] = s * (1.f / 512.f);
}

// ---------------- out[b,j] = zm[b,:] @ cls_w + cls_b ----------------
__global__ __launch_bounds__(256) void k_cls(const float* __restrict__ zm,
                                             const float* __restrict__ w,
                                             const float* __restrict__ bias,
                                             float* __restrict__ out)
{
  int j = blockIdx.x * 256 + threadIdx.x;
  int b = blockIdx.y;
  if (j >= 1000) return;
  float s = bias[j];
  for (int e = 0; e < 256; ++e) s += zm[b * 256 + e] * w[e * 1000 + j];
  out[b * 1000 + j] = s;
}

extern "C" void kernel_launch(void* const* d_in, const int* in_sizes, int n_in,
                              void* d_out, int out_size, void* d_ws, size_t ws_size,
                              hipStream_t stream)
{
  (void)in_sizes; (void)n_in; (void)out_size; (void)ws_size;
  const float* x       = (const float*)d_in[0];
  const float* conv_w  = (const float*)d_in[1];
  const float* conv_b  = (const float*)d_in[2];
  const float* pos_emb = (const float*)d_in[3];
  const float* latents = (const float*)d_in[4];
  const float* ca_wq   = (const float*)d_in[5];
  const float* ca_wk   = (const float*)d_in[6];
  const float* ca_wv   = (const float*)d_in[7];
  const float* ca_wu   = (const float*)d_in[8];
  const float* ca_bu   = (const float*)d_in[9];
  const float* ca_ln_g = (const float*)d_in[10];
  const float* ca_ln_b = (const float*)d_in[11];
  const float* blk_wq  = (const float*)d_in[12];
  const float* blk_wk  = (const float*)d_in[13];
  const float* blk_wv  = (const float*)d_in[14];
  const float* blk_wu  = (const float*)d_in[15];
  const float* blk_bu  = (const float*)d_in[16];
  const float* blk_ln1_g = (const float*)d_in[17];
  const float* blk_ln1_b = (const float*)d_in[18];
  const float* blk_w1  = (const float*)d_in[19];
  const float* blk_b1  = (const float*)d_in[20];
  const float* blk_w2  = (const float*)d_in[21];
  const float* blk_b2  = (const float*)d_in[22];
  const float* blk_ln2_g = (const float*)d_in[23];
  const float* blk_ln2_b = (const float*)d_in[24];
  const float* cls_w   = (const float*)d_in[25];
  const float* cls_b   = (const float*)d_in[26];
  float* out = (float*)d_out;

  float* ws = (float*)d_ws;
  float* regionA = ws;                      // 4,194,304: tokens, later bufK
  float* regionB = regionA + 4194304;       // 4,194,304: qCA|qtilde|Mbuf, later bufV
  float* bufA    = regionB + 4194304;       // 4,194,304: CA T / attn out
  float* bufQ    = bufA + 4194304;          // 4,194,304
  float* Ybig    = bufQ + 4194304;          // 2,097,152 (FF hidden)
  float* z       = Ybig + 2097152;          //   524,288
  float* Y       = z + 524288;              //   524,288
  float* zm      = Y + 524288;              //     1,024

  float* tokens = regionA;
  float* qCA    = regionB;
  float* qtilde = regionB + 1048576;
  float* Mbuf   = regionB + 2097152;
  float* bufK   = regionA;
  float* bufV   = regionB;
  const float scale = 0.17677669529663687f; // 1/sqrt(32)

  k_tokens<<<16384, 256, 0, stream>>>(x, conv_w, conv_b, pos_emb, tokens);

  // qCA = latents @ ca_wq   (512 x 2048)
  k_gemm<false><<<dim3(32, 8, 1), 256, 0, stream>>>(
      latents, ca_wq, qCA, 512, 2048, 256, 256, 2048, 2048, 0, 0, 0);
  // qtilde_h = qCA_h @ wk_h^T   (8 x 512 x 256): fold W_K into Q
  k_gemm<true><<<dim3(4, 8, 8), 256, 0, stream>>>(
      qCA, ca_wk, qtilde, 512, 256, 256, 2048, 2048, 256, 256, 256, 131072);
  // M_h = wv_h @ wu_h   (8 x 256 x 256): fold W_V into W_U
  k_gemm<false><<<dim3(4, 4, 8), 256, 0, stream>>>(
      ca_wv, ca_wu, Mbuf, 256, 256, 256, 2048, 256, 256, 256, 65536, 65536);
  // CA flash attention on tokens: T[b,l,h,c]
  k_flash<<<dim3(16, 8, 4), 256, 0, stream>>>(
      qtilde, tokens, tokens, bufA, 4096,
      256, 256, 256, 2048,
      131072L, 0L, 0L, 1048576L, 0L, 1048576L, 256L, 1048576L, scale);
  // Y = Tflat(2048x2048) @ Mflat(2048x256)
  k_gemm<false><<<dim3(4, 32, 1), 256, 0, stream>>>(
      bufA, Mbuf, Y, 2048, 256, 2048, 2048, 256, 256, 0, 0, 0);
  // z = LN(Y + ca_bu + latents)
  k_bias_res_ln<<<2048, 256, 0, stream>>>(Y, ca_bu, latents, 512, ca_ln_g, ca_ln_b, z);

  for (int d = 0; d < 4; ++d) {
    const float* wq = blk_wq + (long)d * 524288;
    const float* wk = blk_wk + (long)d * 524288;
    const float* wv = blk_wv + (long)d * 524288;
    const float* wu = blk_wu + (long)d * 524288;
    k_gemm<false><<<dim3(32, 32, 1), 256, 0, stream>>>(
        z, wq, bufQ, 2048, 2048, 256, 256, 2048, 2048, 0, 0, 0);
    k_gemm<false><<<dim3(32, 32, 1), 256, 0, stream>>>(
        z, wk, bufK, 2048, 2048, 256, 256, 2048, 2048, 0, 0, 0);
    k_gemm<false><<<dim3(32, 32, 1), 256, 0, stream>>>(
        z, wv, bufV, 2048, 2048, 256, 256, 2048, 2048, 0, 0, 0);
    k_flash<<<dim3(16, 8, 4), 256, 0, stream>>>(
        bufQ, bufK, bufV, bufA, 512,
        2048, 2048, 2048, 2048,
        256L, 1048576L, 256L, 1048576L, 256L, 1048576L, 256L, 1048576L, scale);
    k_gemm<false><<<dim3(4, 32, 1), 256, 0, stream>>>(
        bufA, wu, Y, 2048, 256, 2048, 2048, 256, 256, 0, 0, 0);
    k_bias_res_ln<<<2048, 256, 0, stream>>>(Y, blk_bu + d * 256, z, 2048,
        blk_ln1_g + d * 256, blk_ln1_b + d * 256, z);
    k_gemm<false><<<dim3(16, 32, 1), 256, 0, stream>>>(
        z, blk_w1 + (long)d * 262144, Ybig, 2048, 1024, 256, 256, 1024, 1024, 0, 0, 0);
    k_bias_gelu<<<8192, 256, 0, stream>>>(Ybig, blk_b1 + d * 1024, 1024);
    k_gemm<false><<<dim3(4, 32, 1), 256, 0, stream>>>(
        Ybig, blk_w2 + (long)d * 262144, Y, 2048, 256, 1024, 1024, 256, 256, 0, 0, 0);
    k_bias_res_ln<<<2048, 256, 0, stream>>>(Y, blk_b2 + d * 256, z, 2048,
        blk_ln2_g + d * 256, blk_ln2_b + d * 256, z);
  }

  k_mean<<<4, 256, 0, stream>>>(z, zm);
  k_cls<<<dim3(4, 4), 256, 0, stream>>>(zm, cls_w, cls_b, out);
}

// Round 2
// 995.154 us; speedup vs baseline: 5.0163x; 5.0163x over previous
//
#include <hip/hip_runtime.h>
#include <hip/hip_bf16.h>
#include <math.h>

// Perceiver: B=4,C=3,N=4096,E=256,H=8,FFE=1024,L=512,D=4,NCLS=1000,HS=2048
// bf16 MFMA everywhere GEMM-shaped; fp32 accum; fp32 LN/residual spine.

typedef __attribute__((ext_vector_type(8))) short s8v;   // 8 bf16 = 4 VGPR
typedef __attribute__((ext_vector_type(4))) float f32x4; // MFMA accum

__device__ inline short f2b(float f) {
  union { float f; unsigned u; } a; a.f = f;
  unsigned r = a.u + 0x7fff + ((a.u >> 16) & 1);
  return (short)(r >> 16);
}

// ---------------- tokens(bf16) = conv1x1(x) + bias + pos ----------------
__global__ __launch_bounds__(256) void k_tokens(
    const float* __restrict__ x, const float* __restrict__ cw,
    const float* __restrict__ cb, const float* __restrict__ pe,
    short* __restrict__ tok)
{
  int idx = blockIdx.x * 256 + threadIdx.x;   // B*N*E
  int e = idx & 255;
  int n = (idx >> 8) & 4095;
  int b = idx >> 20;
  float s = cb[e] + pe[n * 256 + e];
#pragma unroll
  for (int c = 0; c < 3; ++c)
    s += x[b * 12288 + c * 4096 + n] * cw[e * 3 + c];
  tok[idx] = f2b(s);
}

// ---------------- transpose: in (R,C) [fp32 or bf16] -> out bf16 (C,R) ----
template<typename TI>
__global__ __launch_bounds__(256) void k_tr(
    const TI* __restrict__ in, short* __restrict__ out,
    int R, int C, long sIn, long sOut)
{
  __shared__ float t[32][33];
  const TI* ib = in + (long)blockIdx.z * sIn;
  short* ob = out + (long)blockIdx.z * sOut;
  int c0 = blockIdx.x * 32, r0 = blockIdx.y * 32;
  int tx = threadIdx.x & 31, ty = threadIdx.x >> 5; // 32 x 8
#pragma unroll
  for (int i = 0; i < 4; ++i)
    t[ty * 4 + i][tx] = (float)ib[(long)(r0 + ty * 4 + i) * C + c0 + tx];
  __syncthreads();
#pragma unroll
  for (int i = 0; i < 4; ++i)
    ob[(long)(c0 + ty * 4 + i) * R + r0 + tx] = f2b(t[tx][ty * 4 + i]);
}

// ---------------- fp32 -> bf16 flat convert ----------------
__global__ __launch_bounds__(256) void k_cvt(const float* __restrict__ in,
                                             short* __restrict__ out)
{
  int i = blockIdx.x * 256 + threadIdx.x;
  out[i] = f2b(in[i]);
}

// ---------------- bf16 MFMA BT-GEMM: C = A(MxK) @ Bt(NxK)^T ----------------
// 128x128 tile, BK=32, 256 thr (4 waves, 2x2 of 64x64). Reg-staged LDS with
// XOR swizzle (byte ^= (row&7)<<4) -> conflict-free ds_read_b128 fragments.
// EPI: 0 = bf16 out, 1 = bias+exact-gelu bf16 out, 2 = fp32 out.
template<int EPI>
__global__ __launch_bounds__(256) void k_mgemm(
    const short* __restrict__ A, const short* __restrict__ Bt,
    void* __restrict__ Cv, const float* __restrict__ bias,
    int K, int lda, int ldb, int ldc,
    long sA, long sB, long sC, int zdA, int zmA, int zdB, int zmB)
{
  __shared__ char As[8192];
  __shared__ char Bs[8192];
  int z = blockIdx.z;
  const short* Ab = A + ((long)((z / zdA) % zmA)) * sA;
  const short* Bb = Bt + ((long)((z / zdB) % zmB)) * sB;
  int t = threadIdx.x;
  int lane = t & 63, w = t >> 6;
  int wr = w >> 1, wc = w & 1;
  int g = lane >> 4, l15 = lane & 15;
  long row0 = (long)blockIdx.y * 128, col0 = (long)blockIdx.x * 128;
  const f32x4 zz = {0.f, 0.f, 0.f, 0.f};
  f32x4 acc[4][4];
#pragma unroll
  for (int m = 0; m < 4; ++m)
#pragma unroll
    for (int n = 0; n < 4; ++n) acc[m][n] = zz;

  for (int k0 = 0; k0 < K; k0 += 32) {
    s8v av[2], bv[2];
#pragma unroll
    for (int i = 0; i < 2; ++i) {
      int idx = i * 256 + t, r = idx >> 2, c = idx & 3;
      av[i] = *(const s8v*)&Ab[(row0 + r) * lda + k0 + c * 8];
      bv[i] = *(const s8v*)&Bb[(col0 + r) * ldb + k0 + c * 8];
    }
    __syncthreads();
#pragma unroll
    for (int i = 0; i < 2; ++i) {
      int idx = i * 256 + t, r = idx >> 2, c = idx & 3;
      int off = (r * 64 + c * 16) ^ ((r & 7) << 4);
      *(s8v*)&As[off] = av[i];
      *(s8v*)&Bs[off] = bv[i];
    }
    __syncthreads();
    s8v af[4], bfr[4];
#pragma unroll
    for (int m = 0; m < 4; ++m) {
      int r = wr * 64 + m * 16 + l15;
      af[m] = *(const s8v*)&As[(r * 64 + g * 16) ^ ((r & 7) << 4)];
    }
#pragma unroll
    for (int n = 0; n < 4; ++n) {
      int r = wc * 64 + n * 16 + l15;
      bfr[n] = *(const s8v*)&Bs[(r * 64 + g * 16) ^ ((r & 7) << 4)];
    }
#pragma unroll
    for (int m = 0; m < 4; ++m)
#pragma unroll
      for (int n = 0; n < 4; ++n)
        acc[m][n] = __builtin_amdgcn_mfma_f32_16x16x32_bf16(af[m], bfr[n], acc[m][n], 0, 0, 0);
  }

  long zo = (long)z * sC;
#pragma unroll
  for (int m = 0; m < 4; ++m)
#pragma unroll
    for (int n = 0; n < 4; ++n)
#pragma unroll
      for (int r = 0; r < 4; ++r) {
        long rr = row0 + wr * 64 + m * 16 + g * 4 + r;
        long cc = col0 + wc * 64 + n * 16 + l15;
        float v = acc[m][n][r];
        if (EPI == 1) {
          v += bias[cc];
          v = 0.5f * v * (1.f + erff(v * 0.70710678118654752f));
        }
        if (EPI == 2)
          ((float*)Cv)[zo + rr * ldc + cc] = v;
        else
          ((short*)Cv)[zo + rr * ldc + cc] = f2b(v);
      }
}

// ---------------- MFMA flash attention (head dim 256) ----------------
// 4 waves x 16 q-rows (QBLK=64), KVBLK=64. K staged (64x256), V staged
// TRANSPOSED (256x64) -- both XOR-swizzled. P relayout via per-wave LDS.
__global__ __launch_bounds__(256, 1) void k_mflash(
    const short* __restrict__ Qp, const short* __restrict__ Kp,
    const short* __restrict__ Vtp, short* __restrict__ Op,
    int nk, int ldq, int ldk, int ldvt, int ldo,
    long qh, long qb, long kh, long kb, long vh, long vb, long oh, long ob,
    float scale)
{
  __shared__ char Ks[32768];
  __shared__ char Vs[32768];
  __shared__ char Ps[8192];
  int h = blockIdx.y, b = blockIdx.z;
  const short* Q  = Qp  + (long)h * qh + (long)b * qb;
  const short* Kg = Kp  + (long)h * kh + (long)b * kb;
  const short* Vg = Vtp + (long)h * vh + (long)b * vb;
  short* O = Op + (long)h * oh + (long)b * ob;
  int t = threadIdx.x, lane = t & 63, w = t >> 6;
  int g = lane >> 4, l15 = lane & 15;
  int q0 = blockIdx.x * 64 + w * 16;
  char* Pw = Ps + w * 2048;

  s8v qf[8];
#pragma unroll
  for (int ks = 0; ks < 8; ++ks)
    qf[ks] = *(const s8v*)&Q[(long)(q0 + l15) * ldq + ks * 32 + g * 8];

  const f32x4 zz = {0.f, 0.f, 0.f, 0.f};
  f32x4 accO[16];
#pragma unroll
  for (int i = 0; i < 16; ++i) accO[i] = zz;
  float mrow[4] = {-1e30f, -1e30f, -1e30f, -1e30f};
  float lrow[4] = {0.f, 0.f, 0.f, 0.f};

  for (int k0 = 0; k0 < nk; k0 += 64) {
    s8v kr[8], vr[8];
#pragma unroll
    for (int i = 0; i < 8; ++i) {
      int idx = i * 256 + t;
      int r1 = idx >> 5, c1 = idx & 31;
      kr[i] = *(const s8v*)&Kg[(long)(k0 + r1) * ldk + c1 * 8];
      int r2 = idx >> 3, c2 = idx & 7;
      vr[i] = *(const s8v*)&Vg[(long)r2 * ldvt + k0 + c2 * 8];
    }
    __syncthreads();
#pragma unroll
    for (int i = 0; i < 8; ++i) {
      int idx = i * 256 + t;
      int r1 = idx >> 5, c1 = idx & 31;
      *(s8v*)&Ks[(r1 * 512 + c1 * 16) ^ ((r1 & 7) << 4)] = kr[i];
      int r2 = idx >> 3, c2 = idx & 7;
      *(s8v*)&Vs[(r2 * 128 + c2 * 16) ^ ((r2 & 7) << 4)] = vr[i];
    }
    __syncthreads();

    // S = Q @ K^T  (16 x 64 per wave)
    f32x4 sacc[4];
#pragma unroll
    for (int kc = 0; kc < 4; ++kc) {
      sacc[kc] = zz;
#pragma unroll
      for (int ks = 0; ks < 8; ++ks) {
        int r = kc * 16 + l15;
        s8v bfr = *(const s8v*)&Ks[(r * 512 + ks * 64 + g * 16) ^ ((r & 7) << 4)];
        sacc[kc] = __builtin_amdgcn_mfma_f32_16x16x32_bf16(qf[ks], bfr, sacc[kc], 0, 0, 0);
      }
#pragma unroll
      for (int r = 0; r < 4; ++r) sacc[kc][r] *= scale;
    }
    // online softmax (rows live in 16-lane groups)
    float mt[4];
#pragma unroll
    for (int r = 0; r < 4; ++r)
      mt[r] = fmaxf(fmaxf(sacc[0][r], sacc[1][r]), fmaxf(sacc[2][r], sacc[3][r]));
#pragma unroll
    for (int o = 1; o < 16; o <<= 1)
#pragma unroll
      for (int r = 0; r < 4; ++r) mt[r] = fmaxf(mt[r], __shfl_xor(mt[r], o));
    float al[4];
#pragma unroll
    for (int r = 0; r < 4; ++r) {
      float mn = fmaxf(mrow[r], mt[r]);
      al[r] = __expf(mrow[r] - mn);
      mrow[r] = mn;
    }
    float lsum[4] = {0.f, 0.f, 0.f, 0.f};
#pragma unroll
    for (int kc = 0; kc < 4; ++kc)
#pragma unroll
      for (int r = 0; r < 4; ++r) {
        float p = __expf(sacc[kc][r] - mrow[r]);
        lsum[r] += p;
        int row = g * 4 + r, col = kc * 16 + l15;
        *(short*)&Pw[(row * 128 + col * 2) ^ ((row & 7) << 4)] = f2b(p);
      }
#pragma unroll
    for (int o = 1; o < 16; o <<= 1)
#pragma unroll
      for (int r = 0; r < 4; ++r) lsum[r] += __shfl_xor(lsum[r], o);
#pragma unroll
    for (int r = 0; r < 4; ++r) lrow[r] = lrow[r] * al[r] + lsum[r];
#pragma unroll
    for (int n = 0; n < 16; ++n)
#pragma unroll
      for (int r = 0; r < 4; ++r) accO[n][r] *= al[r];
    // PV: O += P(16x64) @ V(64x256) using Vt in LDS
    s8v pa[2];
#pragma unroll
    for (int kk = 0; kk < 2; ++kk)
      pa[kk] = *(const s8v*)&Pw[(l15 * 128 + kk * 64 + g * 16) ^ ((l15 & 7) << 4)];
#pragma unroll
    for (int n = 0; n < 16; ++n)
#pragma unroll
      for (int kk = 0; kk < 2; ++kk) {
        int r = n * 16 + l15;
        s8v bv = *(const s8v*)&Vs[(r * 128 + kk * 64 + g * 16) ^ ((r & 7) << 4)];
        accO[n] = __builtin_amdgcn_mfma_f32_16x16x32_bf16(pa[kk], bv, accO[n], 0, 0, 0);
      }
  }
  float inv[4];
#pragma unroll
  for (int r = 0; r < 4; ++r) inv[r] = 1.f / lrow[r];
#pragma unroll
  for (int n = 0; n < 16; ++n)
#pragma unroll
    for (int r = 0; r < 4; ++r)
      O[(long)(q0 + g * 4 + r) * ldo + n * 16 + l15] = f2b(accO[n][r] * inv[r]);
}

// ---------------- z(fp32,bf16) = LN(Y + bias + res) ----------------
__global__ __launch_bounds__(256) void k_bias_res_ln(
    const float* __restrict__ Y, const float* __restrict__ bias,
    const float* __restrict__ res, int resMod,
    const float* __restrict__ g, const float* __restrict__ bta,
    float* __restrict__ out, short* __restrict__ out_bf)
{
  __shared__ float red[4];
  int row = blockIdx.x, e = threadIdx.x;
  float v = Y[(long)row * 256 + e] + bias[e] + res[(long)(row % resMod) * 256 + e];
  float s = v;
#pragma unroll
  for (int o = 32; o > 0; o >>= 1) s += __shfl_down(s, o);
  if ((e & 63) == 0) red[e >> 6] = s;
  __syncthreads();
  float mean = (red[0] + red[1] + red[2] + red[3]) * (1.f / 256.f);
  float d = v - mean;
  __syncthreads();
  float s2 = d * d;
#pragma unroll
  for (int o = 32; o > 0; o >>= 1) s2 += __shfl_down(s2, o);
  if ((e & 63) == 0) red[e >> 6] = s2;
  __syncthreads();
  float var = (red[0] + red[1] + red[2] + red[3]) * (1.f / 256.f);
  float o = g[e] * d * rsqrtf(var + 1e-5f) + bta[e];
  out[(long)row * 256 + e] = o;
  out_bf[(long)row * 256 + e] = f2b(o);
}

// ---------------- zm[b,e] = mean_l z[b,l,e]; cls ----------------
__global__ __launch_bounds__(256) void k_mean(const float* __restrict__ z,
                                              float* __restrict__ zm)
{
  int b = blockIdx.x, e = threadIdx.x;
  float s = 0.f;
  for (int l = 0; l < 512; ++l) s += z[((long)b * 512 + l) * 256 + e];
  zm[b * 256 + e] = s * (1.f / 512.f);
}

__global__ __launch_bounds__(256) void k_cls(const float* __restrict__ zm,
                                             const float* __restrict__ w,
                                             const float* __restrict__ bias,
                                             float* __restrict__ out)
{
  int j = blockIdx.x * 256 + threadIdx.x;
  int b = blockIdx.y;
  if (j >= 1000) return;
  float s = bias[j];
  for (int e = 0; e < 256; ++e) s += zm[b * 256 + e] * w[e * 1000 + j];
  out[b * 1000 + j] = s;
}

extern "C" void kernel_launch(void* const* d_in, const int* in_sizes, int n_in,
                              void* d_out, int out_size, void* d_ws, size_t ws_size,
                              hipStream_t stream)
{
  (void)in_sizes; (void)n_in; (void)out_size; (void)ws_size;
  const float* x       = (const float*)d_in[0];
  const float* conv_w  = (const float*)d_in[1];
  const float* conv_b  = (const float*)d_in[2];
  const float* pos_emb = (const float*)d_in[3];
  const float* latents = (const float*)d_in[4];
  const float* ca_wq   = (const float*)d_in[5];
  const float* ca_wk   = (const float*)d_in[6];
  const float* ca_wv   = (const float*)d_in[7];
  const float* ca_wu   = (const float*)d_in[8];
  const float* ca_bu   = (const float*)d_in[9];
  const float* ca_ln_g = (const float*)d_in[10];
  const float* ca_ln_b = (const float*)d_in[11];
  const float* blk_wq  = (const float*)d_in[12];
  const float* blk_wk  = (const float*)d_in[13];
  const float* blk_wv  = (const float*)d_in[14];
  const float* blk_wu  = (const float*)d_in[15];
  const float* blk_bu  = (const float*)d_in[16];
  const float* blk_ln1_g = (const float*)d_in[17];
  const float* blk_ln1_b = (const float*)d_in[18];
  const float* blk_w1  = (const float*)d_in[19];
  const float* blk_b1  = (const float*)d_in[20];
  const float* blk_w2  = (const float*)d_in[21];
  const float* blk_b2  = (const float*)d_in[22];
  const float* blk_ln2_g = (const float*)d_in[23];
  const float* blk_ln2_b = (const float*)d_in[24];
  const float* cls_w   = (const float*)d_in[25];
  const float* cls_b   = (const float*)d_in[26];
  float* out = (float*)d_out;

  // ---- workspace layout (bf16 as short) ----
  short* wqT_ca = (short*)d_ws;            // 2048x256
  short* wkT_ca = wqT_ca + 524288;         // 2048x256
  short* wuT_ca = wkT_ca + 524288;         // 256x2048
  short* wv_ca  = wuT_ca + 524288;         // 256x2048 (no transpose)
  short* lat_bf = wv_ca + 524288;          // 512x256
  short* wqkT   = lat_bf + 131072;         // 4 x (4096x256)
  short* wvT    = wqkT + 4194304;          // 4 x (2048x256)
  short* wuT_b  = wvT + 2097152;           // 4 x (256x2048)
  short* w1T    = wuT_b + 2097152;         // 4 x (1024x256)
  short* w2T    = w1T + 1048576;           // 4 x (256x1024)
  short* tok_bf = w2T + 1048576;           // 4 x 4096x256
  short* tokT   = tok_bf + 4194304;        // 4 x 256x4096
  short* qCA    = tokT + 4194304;          // 512x2048
  short* qtil   = qCA + 1048576;           // 8 x 512x256
  short* MstT   = qtil + 1048576;          // 256x2048
  short* VtB    = MstT + 524288;           // 32 x 256x512
  short* bufO   = VtB + 4194304;           // 4 x 512x2048
  short* h1     = bufO + 4194304;          // 2048x1024
  short* z_bf   = h1 + 2097152;            // 2048x256
  float* Y      = (float*)(z_bf + 524288); // 2048x256 fp32
  float* z      = Y + 524288;              // 2048x256 fp32
  float* zm     = z + 524288;              // 4x256
  short* QKb    = tok_bf;                  // alias: 4 x 512x4096 (after CA)

  const float scale = 0.17677669529663687f; // 1/sqrt(32)
  const int BIG = 1 << 30;

  // ---- weight prep (bf16, transposed to NxK) ----
  k_tr<float><<<dim3(64, 8, 1), 256, 0, stream>>>(ca_wq, wqT_ca, 256, 2048, 0, 0);
  k_tr<float><<<dim3(64, 8, 1), 256, 0, stream>>>(ca_wk, wkT_ca, 256, 2048, 0, 0);
  k_tr<float><<<dim3(8, 64, 1), 256, 0, stream>>>(ca_wu, wuT_ca, 2048, 256, 0, 0);
  k_cvt<<<2048, 256, 0, stream>>>(ca_wv, wv_ca);
  k_cvt<<<512, 256, 0, stream>>>(latents, lat_bf);
  k_tr<float><<<dim3(64, 8, 4), 256, 0, stream>>>(blk_wq, wqkT, 256, 2048, 524288, 1048576);
  k_tr<float><<<dim3(64, 8, 4), 256, 0, stream>>>(blk_wk, wqkT + 524288, 256, 2048, 524288, 1048576);
  k_tr<float><<<dim3(64, 8, 4), 256, 0, stream>>>(blk_wv, wvT, 256, 2048, 524288, 524288);
  k_tr<float><<<dim3(8, 64, 4), 256, 0, stream>>>(blk_wu, wuT_b, 2048, 256, 524288, 524288);
  k_tr<float><<<dim3(32, 8, 4), 256, 0, stream>>>(blk_w1, w1T, 256, 1024, 262144, 262144);
  k_tr<float><<<dim3(8, 32, 4), 256, 0, stream>>>(blk_w2, w2T, 1024, 256, 262144, 262144);

  // ---- tokens ----
  k_tokens<<<16384, 256, 0, stream>>>(x, conv_w, conv_b, pos_emb, tok_bf);
  k_tr<__hip_bfloat16><<<dim3(8, 128, 4), 256, 0, stream>>>(
      (const __hip_bfloat16*)tok_bf, tokT, 4096, 256, 1048576, 1048576);

  // ---- cross-attention (folded) ----
  // qCA = latents @ ca_wq
  k_mgemm<0><<<dim3(16, 4, 1), 256, 0, stream>>>(
      lat_bf, wqT_ca, qCA, nullptr, 256, 256, 256, 2048, 0, 0, 0, 1, BIG, 1, BIG);
  // qtilde_h = qCA_h @ wk_h^T
  k_mgemm<0><<<dim3(2, 4, 8), 256, 0, stream>>>(
      qCA, wkT_ca, qtil, nullptr, 256, 2048, 256, 256, 256, 65536, 131072, 1, 8, 1, 8);
  // MstT_h = wu_h^T @ wv_h^T  (f x e), stored at cols h*256 of (256x2048)
  k_mgemm<0><<<dim3(2, 2, 8), 256, 0, stream>>>(
      wuT_ca, wv_ca, MstT, nullptr, 256, 2048, 2048, 2048, 256, 256, 256, 1, 8, 1, 8);
  // CA flash: Q=qtilde(h), K=tokens(b), Vt=tokensT(b) -> bufO[b,l,h*256+d]
  k_mflash<<<dim3(8, 8, 4), 256, 0, stream>>>(
      qtil, tok_bf, tokT, bufO, 4096, 256, 256, 4096, 2048,
      131072L, 0L, 0L, 1048576L, 0L, 1048576L, 256L, 1048576L, scale);
  // Y = bufO(2048x2048) @ MstT^T -> fp32
  k_mgemm<2><<<dim3(2, 16, 1), 256, 0, stream>>>(
      bufO, MstT, Y, nullptr, 2048, 2048, 2048, 256, 0, 0, 0, 1, BIG, 1, BIG);
  k_bias_res_ln<<<2048, 256, 0, stream>>>(Y, ca_bu, latents, 512, ca_ln_g, ca_ln_b, z, z_bf);

  // ---- transformer blocks ----
  for (int d = 0; d < 4; ++d) {
    // [Q|K] = z @ [wq wk]  -> QKb (2048 x 4096) bf16
    k_mgemm<0><<<dim3(32, 16, 1), 256, 0, stream>>>(
        z_bf, wqkT + (long)d * 1048576, QKb, nullptr,
        256, 256, 256, 4096, 0, 0, 0, 1, BIG, 1, BIG);
    // Vt(b,h) = wvT_h @ z_b^T  (256 x 512)
    k_mgemm<0><<<dim3(4, 2, 32), 256, 0, stream>>>(
        wvT + (long)d * 524288, z_bf, VtB, nullptr,
        256, 256, 256, 512, 65536, 131072, 131072, 1, 8, 8, BIG);
    // self flash
    k_mflash<<<dim3(8, 8, 4), 256, 0, stream>>>(
        QKb, QKb + 2048, VtB, bufO, 512, 4096, 4096, 512, 2048,
        256L, 2097152L, 256L, 2097152L, 131072L, 1048576L, 256L, 1048576L, scale);
    // Y = bufO @ wu^T -> fp32
    k_mgemm<2><<<dim3(2, 16, 1), 256, 0, stream>>>(
        bufO, wuT_b + (long)d * 524288, Y, nullptr,
        2048, 2048, 2048, 256, 0, 0, 0, 1, BIG, 1, BIG);
    k_bias_res_ln<<<2048, 256, 0, stream>>>(Y, blk_bu + d * 256, z, 2048,
        blk_ln1_g + d * 256, blk_ln1_b + d * 256, z, z_bf);
    // h1 = gelu(z @ w1 + b1)
    k_mgemm<1><<<dim3(8, 16, 1), 256, 0, stream>>>(
        z_bf, w1T + (long)d * 262144, h1, blk_b1 + d * 1024,
        256, 256, 256, 1024, 0, 0, 0, 1, BIG, 1, BIG);
    // Y = h1 @ w2 -> fp32
    k_mgemm<2><<<dim3(2, 16, 1), 256, 0, stream>>>(
        h1, w2T + (long)d * 262144, Y, nullptr,
        1024, 1024, 1024, 256, 0, 0, 0, 1, BIG, 1, BIG);
    k_bias_res_ln<<<2048, 256, 0, stream>>>(Y, blk_b2 + d * 256, z, 2048,
        blk_ln2_g + d * 256, blk_ln2_b + d * 256, z, z_bf);
  }

  k_mean<<<4, 256, 0, stream>>>(z, zm);
  k_cls<<<dim3(4, 4), 256, 0, stream>>>(zm, cls_w, cls_b, out);
}

// Round 3
// 673.134 us; speedup vs baseline: 7.4161x; 1.4784x over previous
//
#include <hip/hip_runtime.h>
#include <hip/hip_bf16.h>
#include <math.h>

// Perceiver: B=4,C=3,N=4096,E=256,H=8,FFE=1024,L=512,D=4,NCLS=1000,HS=2048
// bf16 MFMA everywhere GEMM-shaped; fp32 accum; fp32 LN/residual spine.

typedef __attribute__((ext_vector_type(8))) short s8v;   // 8 bf16 = 4 VGPR
typedef __attribute__((ext_vector_type(4))) float f32x4; // MFMA accum

__device__ __forceinline__ short f2b(float f) {
  union { float f; unsigned u; } a; a.f = f;
  unsigned r = a.u + 0x7fff + ((a.u >> 16) & 1);
  return (short)(r >> 16);
}

// async global->LDS, 16B per lane; LDS dest = uniform base + lane*16
__device__ __forceinline__ void gl16(const void* gp, void* lp) {
  __builtin_amdgcn_global_load_lds(
      (const __attribute__((address_space(1))) unsigned int*)gp,
      (__attribute__((address_space(3))) unsigned int*)lp, 16, 0, 0);
}

// ---------------- tokens(bf16) = conv1x1(x) + bias + pos ----------------
__global__ __launch_bounds__(256) void k_tokens(
    const float* __restrict__ x, const float* __restrict__ cw,
    const float* __restrict__ cb, const float* __restrict__ pe,
    short* __restrict__ tok)
{
  int idx = blockIdx.x * 256 + threadIdx.x;   // B*N*E
  int e = idx & 255;
  int n = (idx >> 8) & 4095;
  int b = idx >> 20;
  float s = cb[e] + pe[n * 256 + e];
#pragma unroll
  for (int c = 0; c < 3; ++c)
    s += x[b * 12288 + c * 4096 + n] * cw[e * 3 + c];
  tok[idx] = f2b(s);
}

// ---------------- transpose: in (R,C) [fp32 or bf16] -> out bf16 (C,R) ----
template<typename TI>
__global__ __launch_bounds__(256) void k_tr(
    const TI* __restrict__ in, short* __restrict__ out,
    int R, int C, long sIn, long sOut)
{
  __shared__ float t[32][33];
  const TI* ib = in + (long)blockIdx.z * sIn;
  short* ob = out + (long)blockIdx.z * sOut;
  int c0 = blockIdx.x * 32, r0 = blockIdx.y * 32;
  int tx = threadIdx.x & 31, ty = threadIdx.x >> 5; // 32 x 8
#pragma unroll
  for (int i = 0; i < 4; ++i)
    t[ty * 4 + i][tx] = (float)ib[(long)(r0 + ty * 4 + i) * C + c0 + tx];
  __syncthreads();
#pragma unroll
  for (int i = 0; i < 4; ++i)
    ob[(long)(c0 + ty * 4 + i) * R + r0 + tx] = f2b(t[tx][ty * 4 + i]);
}

// ---------------- fp32 -> bf16 flat convert ----------------
__global__ __launch_bounds__(256) void k_cvt(const float* __restrict__ in,
                                             short* __restrict__ out)
{
  int i = blockIdx.x * 256 + threadIdx.x;
  out[i] = f2b(in[i]);
}

// ---------------- bf16 MFMA BT-GEMM: C = A(MxK) @ Bt(NxK)^T ----------------
// 128x128 tile, BK=32, 256 thr. Prefetch pipeline: global loads for tile t+1
// issued before compute of tile t. Requires K % 64 == 0.
// EPI: 0 = bf16 out, 1 = bias+exact-gelu bf16 out, 2 = fp32 out (partials).
template<int EPI>
__global__ __launch_bounds__(256) void k_mgemm(
    const short* __restrict__ A, const short* __restrict__ Bt,
    void* __restrict__ Cv, const float* __restrict__ bias,
    int K, int lda, int ldb, int ldc,
    long sA, long sB, long sC, int zdA, int zmA, int zdB, int zmB)
{
  __shared__ char As[8192];
  __shared__ char Bs[8192];
  int z = blockIdx.z;
  const short* Ab = A + ((long)((z / zdA) % zmA)) * sA;
  const short* Bb = Bt + ((long)((z / zdB) % zmB)) * sB;
  int t = threadIdx.x;
  int lane = t & 63, w = t >> 6;
  int wr = w >> 1, wc = w & 1;
  int g = lane >> 4, l15 = lane & 15;
  long row0 = (long)blockIdx.y * 128, col0 = (long)blockIdx.x * 128;
  const f32x4 zz = {0.f, 0.f, 0.f, 0.f};
  f32x4 acc[4][4];
#pragma unroll
  for (int m = 0; m < 4; ++m)
#pragma unroll
    for (int n = 0; n < 4; ++n) acc[m][n] = zz;

  auto mload = [&](s8v* aa, s8v* bb, int kk) {
#pragma unroll
    for (int i = 0; i < 2; ++i) {
      int r = i * 64 + (t >> 2), c = t & 3;
      aa[i] = *(const s8v*)&Ab[(row0 + r) * (long)lda + kk + c * 8];
      bb[i] = *(const s8v*)&Bb[(col0 + r) * (long)ldb + kk + c * 8];
    }
  };
  auto mstore = [&](s8v* aa, s8v* bb) {
#pragma unroll
    for (int i = 0; i < 2; ++i) {
      int r = i * 64 + (t >> 2), c = t & 3;
      int off = (r * 64 + c * 16) ^ ((r & 7) << 4);
      *(s8v*)&As[off] = aa[i];
      *(s8v*)&Bs[off] = bb[i];
    }
  };
  auto mcomp = [&]() {
    s8v af[4], bfr[4];
#pragma unroll
    for (int m = 0; m < 4; ++m) {
      int r = wr * 64 + m * 16 + l15;
      af[m] = *(const s8v*)&As[(r * 64 + g * 16) ^ ((r & 7) << 4)];
    }
#pragma unroll
    for (int n = 0; n < 4; ++n) {
      int r = wc * 64 + n * 16 + l15;
      bfr[n] = *(const s8v*)&Bs[(r * 64 + g * 16) ^ ((r & 7) << 4)];
    }
#pragma unroll
    for (int m = 0; m < 4; ++m)
#pragma unroll
      for (int n = 0; n < 4; ++n)
        acc[m][n] = __builtin_amdgcn_mfma_f32_16x16x32_bf16(af[m], bfr[n], acc[m][n], 0, 0, 0);
  };

  s8v a0[2], b0[2], a1[2], b1[2];
  mload(a0, b0, 0);
  for (int k0 = 0; k0 < K; k0 += 64) {
    __syncthreads(); mstore(a0, b0); __syncthreads();
    mload(a1, b1, k0 + 32);
    mcomp();
    __syncthreads(); mstore(a1, b1); __syncthreads();
    if (k0 + 64 < K) mload(a0, b0, k0 + 64);
    mcomp();
  }

  long zo = (long)z * sC;
#pragma unroll
  for (int m = 0; m < 4; ++m)
#pragma unroll
    for (int n = 0; n < 4; ++n)
#pragma unroll
      for (int r = 0; r < 4; ++r) {
        long rr = row0 + wr * 64 + m * 16 + g * 4 + r;
        long cc = col0 + wc * 64 + n * 16 + l15;
        float v = acc[m][n][r];
        if (EPI == 1) {
          v += bias[cc];
          v = 0.5f * v * (1.f + erff(v * 0.70710678118654752f));
        }
        if (EPI == 2)
          ((float*)Cv)[zo + rr * ldc + cc] = v;
        else
          ((short*)Cv)[zo + rr * ldc + cc] = f2b(v);
      }
}

// ---------------- MFMA flash attention v2 (head dim 256) ----------------
// 512 thr = 8 waves = 2 wavegroups x 4 waves. Each wavegroup processes half
// the KV range (KVBLK=32, double-buffered LDS via global_load_lds), results
// merged through LDS at the end. Per-wave 16 q-rows, QBLK=64.
// LDS per wg (69632B): buf0 K(16K)+V(16K), buf1 K+V, P(4x1K).
__global__ __launch_bounds__(512, 2) void k_mflash2(
    const short* __restrict__ Qp, const short* __restrict__ Kp,
    const short* __restrict__ Vtp, short* __restrict__ Op,
    int nk, int ldq, int ldk, int ldvt, int ldo,
    long qh, long qb, long kh, long kb, long vh, long vb, long oh, long ob,
    float scale)
{
  __shared__ char pool[139264];
  int t = threadIdx.x, lane = t & 63, w = t >> 6;
  int wg = w >> 2, wi = w & 3;
  int g = lane >> 4, l15 = lane & 15;
  int h = blockIdx.y, b = blockIdx.z;
  const short* Q  = Qp  + (long)h * qh + (long)b * qb;
  const short* Kg = Kp  + (long)h * kh + (long)b * kb;
  const short* Vg = Vtp + (long)h * vh + (long)b * vb;
  short* O = Op + (long)h * oh + (long)b * ob;
  char* wpool = pool + wg * 69632;
  char* Pw = wpool + 65536 + wi * 1024;
  int q0 = blockIdx.x * 64 + wi * 16;
  int nkh = nk >> 1;          // keys per wavegroup
  int NIT = nkh >> 5;         // KVBLK = 32
  int k0base = wg * nkh;

  // Q fragments in registers: A-frag row=l15, k = ks*32 + g*8
  const short* Qrow = Q + (long)(q0 + l15) * ldq + g * 8;
  s8v qf[8];
#pragma unroll
  for (int ks = 0; ks < 8; ++ks) qf[ks] = *(const s8v*)(Qrow + ks * 32);

  // staging source pointers (linear LDS dest + inverse-swizzled source)
  // K tile 32x256 bf16, row=512B=32 granules; slot s=wi*256+c*64+lane:
  //   row = wi*8+c*2+(lane>>5), pos = lane&31, src granule = pos ^ (row&7)
  const char* kgRow = (const char*)(Kg + (long)(k0base + wi * 8 + (lane >> 5)) * ldk);
  // V tile 256x32 bf16, row=64B=4 granules; slot s: row = wi*64+c*16+(lane>>2),
  //   pos = lane&3, src granule = pos ^ ((row>>1)&3) = (lane&3)^((lane>>3)&3)
  const char* vgRow = (const char*)(Vg + (long)(wi * 64 + (lane >> 2)) * ldvt + k0base)
                      + ((lane & 3) ^ ((lane >> 3) & 3)) * 16;
  int gk[4];
#pragma unroll
  for (int c = 0; c < 4; ++c) gk[c] = ((lane & 31) ^ (c * 2 + (lane >> 5))) * 16;

  auto stage = [&](int bsel) {
    char* kd = wpool + bsel * 32768 + wi * 4096;
    char* vd = wpool + bsel * 32768 + 16384 + wi * 4096;
#pragma unroll
    for (int c = 0; c < 4; ++c)
      gl16(kgRow + (long)c * (4 * ldk) + gk[c], kd + c * 1024);
#pragma unroll
    for (int c = 0; c < 4; ++c)
      gl16(vgRow + (long)c * (32 * ldvt), vd + c * 1024);
  };

  const f32x4 zz = {0.f, 0.f, 0.f, 0.f};
  f32x4 accO[16];
#pragma unroll
  for (int i = 0; i < 16; ++i) accO[i] = zz;
  float mrow[4] = {-1e30f, -1e30f, -1e30f, -1e30f};
  float lrow[4] = {0.f, 0.f, 0.f, 0.f};

  stage(0);
  kgRow += (long)64 * ldk; vgRow += 64;

  for (int it = 0; it < NIT; ++it) {
    int cur = it & 1;
    asm volatile("s_waitcnt vmcnt(0)" ::: "memory");
    __syncthreads();
    if (it + 1 < NIT) {           // prefetch next tile: overlaps with compute
      stage(cur ^ 1);
      kgRow += (long)64 * ldk; vgRow += 64;
    }
    const char* kls = wpool + cur * 32768;
    const char* vls = kls + 16384;

    // S = Q @ K^T (16x32 per wave)
    f32x4 sacc[2];
    __builtin_amdgcn_s_setprio(1);
#pragma unroll
    for (int kc = 0; kc < 2; ++kc) {
      sacc[kc] = zz;
#pragma unroll
      for (int ks = 0; ks < 8; ++ks) {
        s8v bfr = *(const s8v*)&kls[(kc * 16 + l15) * 512 + (((ks * 4 + g) ^ (l15 & 7)) * 16)];
        sacc[kc] = __builtin_amdgcn_mfma_f32_16x16x32_bf16(qf[ks], bfr, sacc[kc], 0, 0, 0);
      }
    }
    __builtin_amdgcn_s_setprio(0);

    // online softmax; rows live in 16-lane groups (row = g*4+r)
#pragma unroll
    for (int kc = 0; kc < 2; ++kc)
#pragma unroll
      for (int r = 0; r < 4; ++r) sacc[kc][r] *= scale;
    float mt[4];
#pragma unroll
    for (int r = 0; r < 4; ++r) mt[r] = fmaxf(sacc[0][r], sacc[1][r]);
#pragma unroll
    for (int o = 1; o < 16; o <<= 1)
#pragma unroll
      for (int r = 0; r < 4; ++r) mt[r] = fmaxf(mt[r], __shfl_xor(mt[r], o));
    // defer-max (T13): only rescale when max grew by > 8
    float dmax = fmaxf(fmaxf(mt[0] - mrow[0], mt[1] - mrow[1]),
                       fmaxf(mt[2] - mrow[2], mt[3] - mrow[3]));
    if (__any(dmax > 8.f)) {
#pragma unroll
      for (int r = 0; r < 4; ++r) {
        float mn = fmaxf(mrow[r], mt[r]);
        float al = __expf(mrow[r] - mn);
        mrow[r] = mn; lrow[r] *= al;
#pragma unroll
        for (int n = 0; n < 16; ++n) accO[n][r] *= al;
      }
    }
    float ps[2][4], lsum[4] = {0.f, 0.f, 0.f, 0.f};
#pragma unroll
    for (int kc = 0; kc < 2; ++kc)
#pragma unroll
      for (int r = 0; r < 4; ++r) {
        float p = __expf(sacc[kc][r] - mrow[r]);
        ps[kc][r] = p; lsum[r] += p;
      }
#pragma unroll
    for (int o = 1; o < 16; o <<= 1)
#pragma unroll
      for (int r = 0; r < 4; ++r) lsum[r] += __shfl_xor(lsum[r], o);
#pragma unroll
    for (int r = 0; r < 4; ++r) lrow[r] += lsum[r];

    // P -> per-wave LDS (bf16), byte-swizzle ^(g<<4) within 64B row
#pragma unroll
    for (int kc = 0; kc < 2; ++kc)
#pragma unroll
      for (int r = 0; r < 4; ++r)
        *(short*)&Pw[(g * 4 + r) * 64 + ((kc * 32 + l15 * 2) ^ (g << 4))] = f2b(ps[kc][r]);
    s8v pa = *(const s8v*)&Pw[l15 * 64 + ((g * 16) ^ ((l15 >> 2) << 4))];

    // O += P(16x32) @ V(32x256) via Vt in LDS
    __builtin_amdgcn_s_setprio(1);
#pragma unroll
    for (int n = 0; n < 16; ++n) {
      s8v vf = *(const s8v*)&vls[(n * 16 + l15) * 64 + ((g ^ ((l15 >> 1) & 3)) * 16)];
      accO[n] = __builtin_amdgcn_mfma_f32_16x16x32_bf16(pa, vf, accO[n], 0, 0, 0);
    }
    __builtin_amdgcn_s_setprio(0);
  }

  // merge wavegroup partials through LDS (wg1 -> wg0)
  __syncthreads();
  float* mrg = (float*)(pool + 69632);          // [64][260] fp32
  float* mlA = (float*)(pool + 69632 + 66560);  // [64][2] (m, l)
  if (wg == 1) {
#pragma unroll
    for (int n = 0; n < 16; ++n)
#pragma unroll
      for (int r = 0; r < 4; ++r)
        mrg[(wi * 16 + g * 4 + r) * 260 + n * 16 + l15] = accO[n][r];
    if (l15 == 0) {
#pragma unroll
      for (int r = 0; r < 4; ++r) {
        mlA[(wi * 16 + g * 4 + r) * 2] = mrow[r];
        mlA[(wi * 16 + g * 4 + r) * 2 + 1] = lrow[r];
      }
    }
  }
  __syncthreads();
  if (wg == 0) {
    float inv[4];
#pragma unroll
    for (int r = 0; r < 4; ++r) {
      int row = wi * 16 + g * 4 + r;
      float m1 = mlA[row * 2], l1 = mlA[row * 2 + 1];
      float mn = fmaxf(mrow[r], m1);
      float ea = __expf(mrow[r] - mn), eb = __expf(m1 - mn);
      lrow[r] = lrow[r] * ea + l1 * eb;
      inv[r] = 1.f / lrow[r];
#pragma unroll
      for (int n = 0; n < 16; ++n)
        accO[n][r] = accO[n][r] * ea + mrg[row * 260 + n * 16 + l15] * eb;
    }
#pragma unroll
    for (int n = 0; n < 16; ++n)
#pragma unroll
      for (int r = 0; r < 4; ++r)
        O[(long)(q0 + g * 4 + r) * ldo + n * 16 + l15] = f2b(accO[n][r] * inv[r]);
  }
}

// ---------------- z = LN(sum(Ypart) + bias + res) ----------------
__global__ __launch_bounds__(256) void k_bias_res_ln(
    const float* __restrict__ Yp, int nPart, long pStride,
    const float* __restrict__ bias,
    const float* __restrict__ res, int resMod,
    const float* __restrict__ g, const float* __restrict__ bta,
    float* __restrict__ out, short* __restrict__ out_bf)
{
  __shared__ float red[4];
  int row = blockIdx.x, e = threadIdx.x;
  float v = bias[e] + res[(long)(row % resMod) * 256 + e];
  for (int s = 0; s < nPart; ++s) v += Yp[s * pStride + (long)row * 256 + e];
  float s1 = v;
#pragma unroll
  for (int o = 32; o > 0; o >>= 1) s1 += __shfl_down(s1, o);
  if ((e & 63) == 0) red[e >> 6] = s1;
  __syncthreads();
  float mean = (red[0] + red[1] + red[2] + red[3]) * (1.f / 256.f);
  float d = v - mean;
  __syncthreads();
  float s2 = d * d;
#pragma unroll
  for (int o = 32; o > 0; o >>= 1) s2 += __shfl_down(s2, o);
  if ((e & 63) == 0) red[e >> 6] = s2;
  __syncthreads();
  float var = (red[0] + red[1] + red[2] + red[3]) * (1.f / 256.f);
  float o = g[e] * d * rsqrtf(var + 1e-5f) + bta[e];
  out[(long)row * 256 + e] = o;
  out_bf[(long)row * 256 + e] = f2b(o);
}

// ---------------- zm[b,e] = mean_l z[b,l,e]; cls ----------------
__global__ __launch_bounds__(256) void k_mean(const float* __restrict__ z,
                                              float* __restrict__ zm)
{
  int b = blockIdx.x, e = threadIdx.x;
  float s = 0.f;
  for (int l = 0; l < 512; ++l) s += z[((long)b * 512 + l) * 256 + e];
  zm[b * 256 + e] = s * (1.f / 512.f);
}

__global__ __launch_bounds__(256) void k_cls(const float* __restrict__ zm,
                                             const float* __restrict__ w,
                                             const float* __restrict__ bias,
                                             float* __restrict__ out)
{
  int j = blockIdx.x * 256 + threadIdx.x;
  int b = blockIdx.y;
  if (j >= 1000) return;
  float s = bias[j];
  for (int e = 0; e < 256; ++e) s += zm[b * 256 + e] * w[e * 1000 + j];
  out[b * 1000 + j] = s;
}

extern "C" void kernel_launch(void* const* d_in, const int* in_sizes, int n_in,
                              void* d_out, int out_size, void* d_ws, size_t ws_size,
                              hipStream_t stream)
{
  (void)in_sizes; (void)n_in; (void)out_size; (void)ws_size;
  const float* x       = (const float*)d_in[0];
  const float* conv_w  = (const float*)d_in[1];
  const float* conv_b  = (const float*)d_in[2];
  const float* pos_emb = (const float*)d_in[3];
  const float* latents = (const float*)d_in[4];
  const float* ca_wq   = (const float*)d_in[5];
  const float* ca_wk   = (const float*)d_in[6];
  const float* ca_wv   = (const float*)d_in[7];
  const float* ca_wu   = (const float*)d_in[8];
  const float* ca_bu   = (const float*)d_in[9];
  const float* ca_ln_g = (const float*)d_in[10];
  const float* ca_ln_b = (const float*)d_in[11];
  const float* blk_wq  = (const float*)d_in[12];
  const float* blk_wk  = (const float*)d_in[13];
  const float* blk_wv  = (const float*)d_in[14];
  const float* blk_wu  = (const float*)d_in[15];
  const float* blk_bu  = (const float*)d_in[16];
  const float* blk_ln1_g = (const float*)d_in[17];
  const float* blk_ln1_b = (const float*)d_in[18];
  const float* blk_w1  = (const float*)d_in[19];
  const float* blk_b1  = (const float*)d_in[20];
  const float* blk_w2  = (const float*)d_in[21];
  const float* blk_b2  = (const float*)d_in[22];
  const float* blk_ln2_g = (const float*)d_in[23];
  const float* blk_ln2_b = (const float*)d_in[24];
  const float* cls_w   = (const float*)d_in[25];
  const float* cls_b   = (const float*)d_in[26];
  float* out = (float*)d_out;

  // ---- workspace layout (bf16 as short) ----
  short* wqT_ca = (short*)d_ws;            // 2048x256
  short* wkT_ca = wqT_ca + 524288;         // 2048x256
  short* wuT_ca = wkT_ca + 524288;         // 256x2048
  short* wv_ca  = wuT_ca + 524288;         // 256x2048
  short* lat_bf = wv_ca + 524288;          // 512x256
  short* wqkT   = lat_bf + 131072;         // 4 x (4096x256)
  short* wvT    = wqkT + 4194304;          // 4 x (2048x256)
  short* wuT_b  = wvT + 2097152;           // 4 x (256x2048)
  short* w1T    = wuT_b + 2097152;         // 4 x (1024x256)
  short* w2T    = w1T + 1048576;           // 4 x (256x1024)
  short* tok_bf = w2T + 1048576;           // 4 x 4096x256
  short* tokT   = tok_bf + 4194304;        // 4 x 256x4096
  short* qCA    = tokT + 4194304;          // 512x2048
  short* qtil   = qCA + 1048576;           // 8 x 512x256
  short* MstT   = qtil + 1048576;          // 256x2048
  short* VtB    = MstT + 524288;           // 32 x 256x512
  short* bufO   = VtB + 4194304;           // 4 x 512x2048
  short* h1     = bufO + 4194304;          // 2048x1024
  short* z_bf   = h1 + 2097152;            // 2048x256
  float* z      = (float*)(z_bf + 524288); // 2048x256 fp32
  float* zm     = z + 524288;              // 4x256
  float* Ypart  = zm + 1024;               // 8 x 2048x256 fp32 (split-K partials)
  short* QKb    = tok_bf;                  // alias: 2048x4096 (after CA)

  const float scale = 0.17677669529663687f; // 1/sqrt(32)
  const int BIG = 1 << 30;

  // ---- weight prep (bf16, transposed to NxK) ----
  k_tr<float><<<dim3(64, 8, 1), 256, 0, stream>>>(ca_wq, wqT_ca, 256, 2048, 0, 0);
  k_tr<float><<<dim3(64, 8, 1), 256, 0, stream>>>(ca_wk, wkT_ca, 256, 2048, 0, 0);
  k_tr<float><<<dim3(8, 64, 1), 256, 0, stream>>>(ca_wu, wuT_ca, 2048, 256, 0, 0);
  k_cvt<<<2048, 256, 0, stream>>>(ca_wv, wv_ca);
  k_cvt<<<512, 256, 0, stream>>>(latents, lat_bf);
  k_tr<float><<<dim3(64, 8, 4), 256, 0, stream>>>(blk_wq, wqkT, 256, 2048, 524288, 1048576);
  k_tr<float><<<dim3(64, 8, 4), 256, 0, stream>>>(blk_wk, wqkT + 524288, 256, 2048, 524288, 1048576);
  k_tr<float><<<dim3(64, 8, 4), 256, 0, stream>>>(blk_wv, wvT, 256, 2048, 524288, 524288);
  k_tr<float><<<dim3(8, 64, 4), 256, 0, stream>>>(blk_wu, wuT_b, 2048, 256, 524288, 524288);
  k_tr<float><<<dim3(32, 8, 4), 256, 0, stream>>>(blk_w1, w1T, 256, 1024, 262144, 262144);
  k_tr<float><<<dim3(8, 32, 4), 256, 0, stream>>>(blk_w2, w2T, 1024, 256, 262144, 262144);

  // ---- tokens ----
  k_tokens<<<16384, 256, 0, stream>>>(x, conv_w, conv_b, pos_emb, tok_bf);
  k_tr<__hip_bfloat16><<<dim3(8, 128, 4), 256, 0, stream>>>(
      (const __hip_bfloat16*)tok_bf, tokT, 4096, 256, 1048576, 1048576);

  // ---- cross-attention (W_K folded into Q; W_V*W_U folded into MstT) ----
  k_mgemm<0><<<dim3(16, 4, 1), 256, 0, stream>>>(
      lat_bf, wqT_ca, qCA, nullptr, 256, 256, 256, 2048, 0, 0, 0, 1, BIG, 1, BIG);
  k_mgemm<0><<<dim3(2, 4, 8), 256, 0, stream>>>(
      qCA, wkT_ca, qtil, nullptr, 256, 2048, 256, 256, 256, 65536, 131072, 1, 8, 1, 8);
  k_mgemm<0><<<dim3(2, 2, 8), 256, 0, stream>>>(
      wuT_ca, wv_ca, MstT, nullptr, 256, 2048, 2048, 2048, 256, 256, 256, 1, 8, 1, 8);
  // CA flash: Q=qtilde(h), K=tokens(b), Vt=tokensT(b) -> bufO[b,l,h*256+d]
  k_mflash2<<<dim3(8, 8, 4), 512, 0, stream>>>(
      qtil, tok_bf, tokT, bufO, 4096, 256, 256, 4096, 2048,
      131072L, 0L, 0L, 1048576L, 0L, 1048576L, 256L, 1048576L, scale);
  // Y = bufO(2048x2048) @ MstT^T, split-K x8 -> fp32 partials
  k_mgemm<2><<<dim3(2, 16, 8), 256, 0, stream>>>(
      bufO, MstT, Ypart, nullptr, 256, 2048, 2048, 256, 256, 256, 524288, 1, 8, 1, 8);
  k_bias_res_ln<<<2048, 256, 0, stream>>>(Ypart, 8, 524288L, ca_bu, latents, 512,
                                          ca_ln_g, ca_ln_b, z, z_bf);

  // ---- transformer blocks ----
  for (int d = 0; d < 4; ++d) {
    // [Q|K] = z @ [wq wk]  -> QKb (2048 x 4096) bf16
    k_mgemm<0><<<dim3(32, 16, 1), 256, 0, stream>>>(
        z_bf, wqkT + (long)d * 1048576, QKb, nullptr,
        256, 256, 256, 4096, 0, 0, 0, 1, BIG, 1, BIG);
    // Vt(b,h) = wvT_h @ z_b^T  (256 x 512)
    k_mgemm<0><<<dim3(4, 2, 32), 256, 0, stream>>>(
        wvT + (long)d * 524288, z_bf, VtB, nullptr,
        256, 256, 256, 512, 65536, 131072, 131072, 1, 8, 8, BIG);
    // self flash
    k_mflash2<<<dim3(8, 8, 4), 512, 0, stream>>>(
        QKb, QKb + 2048, VtB, bufO, 512, 4096, 4096, 512, 2048,
        256L, 2097152L, 256L, 2097152L, 131072L, 1048576L, 256L, 1048576L, scale);
    // Y = bufO @ wu^T, split-K x8 -> fp32 partials
    k_mgemm<2><<<dim3(2, 16, 8), 256, 0, stream>>>(
        bufO, wuT_b + (long)d * 524288, Ypart, nullptr,
        256, 2048, 2048, 256, 256, 256, 524288, 1, 8, 1, 8);
    k_bias_res_ln<<<2048, 256, 0, stream>>>(Ypart, 8, 524288L, blk_bu + d * 256, z, 2048,
        blk_ln1_g + d * 256, blk_ln1_b + d * 256, z, z_bf);
    // h1 = gelu(z @ w1 + b1)
    k_mgemm<1><<<dim3(8, 16, 1), 256, 0, stream>>>(
        z_bf, w1T + (long)d * 262144, h1, blk_b1 + d * 1024,
        256, 256, 256, 1024, 0, 0, 0, 1, BIG, 1, BIG);
    // Y = h1 @ w2, split-K x8 (Ksub=128) -> fp32 partials
    k_mgemm<2><<<dim3(2, 16, 8), 256, 0, stream>>>(
        h1, w2T + (long)d * 262144, Ypart, nullptr,
        128, 1024, 1024, 256, 128, 128, 524288, 1, 8, 1, 8);
    k_bias_res_ln<<<2048, 256, 0, stream>>>(Ypart, 8, 524288L, blk_b2 + d * 256, z, 2048,
        blk_ln2_g + d * 256, blk_ln2_b + d * 256, z, z_bf);
  }

  k_mean<<<4, 256, 0, stream>>>(z, zm);
  k_cls<<<dim3(4, 4), 256, 0, stream>>>(zm, cls_w, cls_b, out);
}